// Round 2
// baseline (244.386 us; speedup 1.0000x reference)
//
#include <hip/hip_runtime.h>

// PatchMatch stereo — MI355X (gfx950)
// B=1, C=32, H=128, W=256, S=12, FILTER=3, TEMP=7, ITERATIONS=2
// 4 rounds (h,v,h,v); noise ping-pongs noise->ws0->d_out->ws0,
// final round writes disp into d_out (full overwrite).
//
// R1: grid(H,S) with h fastest => all 12 s-blocks of a row share an XCD
//     (linear ids h+128k, 128%8==0) — cuts cross-XCD L2 fill duplication
//     (FETCH_SIZE 71.8MB -> ~12MB/round). float4 staging + ds_write_b128.

namespace {
constexpr int C = 32;
constexpr int H = 128;
constexpr int W = 256;
constexpr int S = 12;
constexpr int HW = H * W;
constexpr int PITCH = 264;            // W + 8: 4 front pad + 4 back pad, 16B-aligned
constexpr int FRONT = 4;              // data at [4 .. 259]
constexpr float TEMP_OVER_C = 7.0f / 32.0f;
constexpr float INTERVAL = 1.0f / (S + 1);
}

template <int HORIZ>
__global__ __launch_bounds__(256, 4) void pm_round(
    const float* __restrict__ left,
    const float* __restrict__ right,
    const float* __restrict__ min_disp,
    const float* __restrict__ max_disp,
    const float* __restrict__ noise_in,
    float* __restrict__ noise_out,
    float* __restrict__ disp_out,
    int write_noise, int write_disp)
{
    __shared__ float sR[C * PITCH];

    const int w = threadIdx.x;          // pixel x
    const int h = blockIdx.x;           // row   (fastest -> XCD locality)
    const int s = blockIdx.y;           // sample group
    const int row = h * W;

    // ---- stage right[:, h, :] channel-major into LDS via float4 ----
    // 32 ch x 64 float4 = 2048 float4; 256 threads x 8
    #pragma unroll
    for (int i = 0; i < 8; ++i) {
        const int f = w + 256 * i;          // flat float4 index
        const int c = f >> 6;               // f / 64
        const int x4 = f & 63;              // float4 within row
        const float4 v = *(const float4*)&right[c * HW + row + (x4 << 2)];
        *(float4*)&sR[c * PITCH + FRONT + (x4 << 2)] = v;
    }
    // zero the pads: 8 pad floats per channel x 32 ch = 256 -> one per thread
    {
        const int c = w >> 3;
        const int j = w & 7;
        const int idx = (j < 4) ? j : (W + j);   // [0..3] front, [260..263] back
        sR[c * PITCH + idx] = 0.0f;
    }

    // ---- left pixel column into registers ----
    float la[C];
    #pragma unroll
    for (int c = 0; c < C; ++c)
        la[c] = left[c * HW + row + w];

    __syncthreads();

    const float mind = fmaxf(min_disp[row + w], 0.0f);
    const float maxd = fmaxf(max_disp[row + w], 0.0f);
    const float search = maxd - mind;
    const float sc = search * INTERVAL;                 // noise scale
    const float imin = fmaf(sc, (float)(s + 1), mind);  // interval_min[s]

    float cost[3], dsamp[3], nsamp[3];

    #pragma unroll
    for (int c = 0; c < 3; ++c) {
        // propagated noise tap
        float np;
        if (HORIZ) {
            int x = w + c - 1;
            np = (x >= 0 && x < W) ? noise_in[s * HW + row + x] : 0.0f;
        } else {
            int y = h + c - 1;
            np = (y >= 0 && y < H) ? noise_in[s * HW + y * W + w] : 0.0f;
        }
        nsamp[c] = np;
        const float disp = fmaf(np, sc, imin);
        dsamp[c] = disp;

        // bilinear sample position in right image
        const float xs = (float)w - disp;
        const float x0f = floorf(xs);
        const float frac = xs - x0f;
        const int x0 = (int)x0f;
        const float v0 = (x0 >= 0 && x0 < W) ? 1.0f : 0.0f;
        const float v1 = (x0 >= -1 && x0 < W - 1) ? 1.0f : 0.0f;
        int base = x0 < -1 ? -1 : (x0 > W - 1 ? W - 1 : x0);

        const float* p = &sR[base + FRONT];
        float d0 = 0.0f, d1 = 0.0f;
        #pragma unroll
        for (int k = 0; k < C; ++k) {
            const float g0 = p[0];
            const float g1 = p[1];      // adjacent -> ds_read2_b32
            d0 = fmaf(la[k], g0, d0);
            d1 = fmaf(la[k], g1, d1);
            p += PITCH;
        }
        const float w0 = (1.0f - frac) * v0;
        const float w1 = frac * v1;
        cost[c] = (w0 * d0 + w1 * d1) * TEMP_OVER_C;
    }

    // softmax over the 3 filter taps
    const float m = fmaxf(cost[0], fmaxf(cost[1], cost[2]));
    const float e0 = __expf(cost[0] - m);
    const float e1 = __expf(cost[1] - m);
    const float e2 = __expf(cost[2] - m);
    const float inv = 1.0f / (e0 + e1 + e2);
    const float ds = (e0 * dsamp[0] + e1 * dsamp[1] + e2 * dsamp[2]) * inv;
    const float dn = (e0 * nsamp[0] + e1 * nsamp[1] + e2 * nsamp[2]) * inv;

    const int o = s * HW + row + w;
    if (write_noise) noise_out[o] = dn;
    if (write_disp)  disp_out[o]  = ds;
}

extern "C" void kernel_launch(void* const* d_in, const int* in_sizes, int n_in,
                              void* d_out, int out_size, void* d_ws, size_t ws_size,
                              hipStream_t stream) {
    const float* left   = (const float*)d_in[0];
    const float* right  = (const float*)d_in[1];
    const float* mind   = (const float*)d_in[2];
    const float* maxd   = (const float*)d_in[3];
    const float* noise  = (const float*)d_in[4];
    float* out = (float*)d_out;
    float* ws0 = (float*)d_ws;          // S*H*W floats = 1.5 MB

    dim3 grid(H, S);                    // h fastest -> XCD locality
    dim3 block(256);

    // r0: horizontal, noise -> ws0
    pm_round<1><<<grid, block, 0, stream>>>(left, right, mind, maxd, noise, ws0, out, 1, 0);
    // r1: vertical,   ws0 -> d_out (as noise scratch)
    pm_round<0><<<grid, block, 0, stream>>>(left, right, mind, maxd, ws0, out, out, 1, 0);
    // r2: horizontal, d_out -> ws0
    pm_round<1><<<grid, block, 0, stream>>>(left, right, mind, maxd, out, ws0, out, 1, 0);
    // r3: vertical,   ws0 -> (no noise write), disp -> d_out (full overwrite)
    pm_round<0><<<grid, block, 0, stream>>>(left, right, mind, maxd, ws0, ws0, out, 0, 1);
}

// Round 4
// 197.287 us; speedup vs baseline: 1.2387x; 1.2387x over previous
//
#include <hip/hip_runtime.h>
#include <hip/hip_cooperative_groups.h>

namespace cg = cooperative_groups;

// PatchMatch stereo — MI355X (gfx950), fused cooperative version (R3).
// B=1, C=32, H=128, W=256, S=12, FILTER=3, TEMP=7, ITERATIONS=2
// Rounds h,v,h,v fused into ONE kernel with 2 grid.sync()s.
// Grid 512 blocks (128 rows x 4 s-triples), launch_bounds(256,2):
//   VGPR cap 256, LDS 37KB -> guaranteed 2 blocks/CU -> coop grid 512 fits.
// Round1->Round2 noise passes through LDS (same-block, same-row dependency).
// Checked fallback: if coop launch is rejected, run a 3-kernel split
// (r0 / r1+r2-fused / r3) producing identical results.

namespace {
constexpr int C = 32;
constexpr int H = 128;
constexpr int W = 256;
constexpr int S = 12;
constexpr int SG = 3;                 // s-groups per block
constexpr int GY = S / SG;            // 4
constexpr int HW = H * W;
constexpr int PITCH = 264;            // W + 8: 4 front, 4 back pad (16B aligned)
constexpr int FRONT = 4;
constexpr int NPITCH = W + 2;         // LDS noise row: 1 front, 1 back pad
constexpr float TEMP_OVER_C = 7.0f / 32.0f;
constexpr float INTERVAL = 1.0f / (S + 1);
}

__device__ __forceinline__ void eval_sample(
    const float* __restrict__ sR, const float la[C], int w,
    float imin, float sc, const float np[3], float& ds_out, float& dn_out)
{
    float cost[3], dsamp[3];
    #pragma unroll
    for (int c = 0; c < 3; ++c) {
        const float disp = fmaf(np[c], sc, imin);
        dsamp[c] = disp;
        const float xs = (float)w - disp;
        const float x0f = floorf(xs);
        const float frac = xs - x0f;
        const int x0 = (int)x0f;
        const float v0 = (x0 >= 0 && x0 < W) ? 1.0f : 0.0f;
        const float v1 = (x0 >= -1 && x0 < W - 1) ? 1.0f : 0.0f;
        const int base = x0 < -1 ? -1 : (x0 > W - 1 ? W - 1 : x0);

        const float* p = &sR[base + FRONT];
        float d0a = 0.f, d0b = 0.f, d1a = 0.f, d1b = 0.f;
        #pragma unroll
        for (int k = 0; k < C; k += 2) {
            d0a = fmaf(la[k],     p[0],         d0a);
            d1a = fmaf(la[k],     p[1],         d1a);     // ds_read2_b32
            d0b = fmaf(la[k + 1], p[PITCH],     d0b);
            d1b = fmaf(la[k + 1], p[PITCH + 1], d1b);
            p += 2 * PITCH;
        }
        const float w0 = (1.0f - frac) * v0;
        const float w1 = frac * v1;
        cost[c] = (w0 * (d0a + d0b) + w1 * (d1a + d1b)) * TEMP_OVER_C;
    }
    const float m = fmaxf(cost[0], fmaxf(cost[1], cost[2]));
    const float e0 = __expf(cost[0] - m);
    const float e1 = __expf(cost[1] - m);
    const float e2 = __expf(cost[2] - m);
    const float inv = 1.0f / (e0 + e1 + e2);
    ds_out = (e0 * dsamp[0] + e1 * dsamp[1] + e2 * dsamp[2]) * inv;
    dn_out = (e0 * np[0] + e1 * np[1] + e2 * np[2]) * inv;
}

// Stage right row (channel-major, padded) into sR, left column into la,
// compute per-pixel disparity-range state.
__device__ __forceinline__ void stage_block(
    const float* __restrict__ left, const float* __restrict__ right,
    const float* __restrict__ min_disp, const float* __restrict__ max_disp,
    float* sR, int w, int row, float la[C], float& sc, float imin[SG], int s0)
{
    #pragma unroll
    for (int i = 0; i < 8; ++i) {
        const int f = w + 256 * i;
        const int c = f >> 6;
        const int x4 = f & 63;
        const float4 v = *(const float4*)&right[c * HW + row + (x4 << 2)];
        *(float4*)&sR[c * PITCH + FRONT + (x4 << 2)] = v;
    }
    {   // zero pads: 8 per channel x 32 ch = 256 -> one per thread
        const int c = w >> 3;
        const int j = w & 7;
        const int idx = (j < 4) ? j : (W + j);
        sR[c * PITCH + idx] = 0.0f;
    }
    #pragma unroll
    for (int c = 0; c < C; ++c)
        la[c] = left[c * HW + row + w];

    const float mind = fmaxf(min_disp[row + w], 0.0f);
    const float maxd = fmaxf(max_disp[row + w], 0.0f);
    sc = (maxd - mind) * INTERVAL;
    #pragma unroll
    for (int si = 0; si < SG; ++si)
        imin[si] = fmaf(sc, (float)(s0 + si + 1), mind);
}

__global__ __launch_bounds__(256, 2) void pm_fused(
    const float* __restrict__ left,
    const float* __restrict__ right,
    const float* __restrict__ min_disp,
    const float* __restrict__ max_disp,
    const float* __restrict__ noise_in,
    float* __restrict__ nbuf0,
    float* __restrict__ nbuf1,
    float* __restrict__ disp_out)
{
    __shared__ float sR[C * PITCH];
    __shared__ float sN[SG * NPITCH];

    const int w  = threadIdx.x;
    const int h  = blockIdx.x;          // fastest -> XCD locality
    const int s0 = SG * blockIdx.y;
    const int row = h * W;

    float la[C], sc, imin[SG];
    stage_block(left, right, min_disp, max_disp, sR, w, row, la, sc, imin, s0);
    if (w < SG) {                       // sN edge pads stay zero
        sN[w * NPITCH + 0]     = 0.0f;
        sN[w * NPITCH + W + 1] = 0.0f;
    }
    __syncthreads();

    cg::grid_group grid = cg::this_grid();

    // ---- round 0: horizontal, noise_in -> nbuf0 ----
    #pragma unroll 1
    for (int si = 0; si < SG; ++si) {
        const int s = s0 + si;
        float np[3];
        #pragma unroll
        for (int c = 0; c < 3; ++c) {
            const int x = w + c - 1;
            np[c] = (x >= 0 && x < W) ? noise_in[s * HW + row + x] : 0.0f;
        }
        float ds, dn;
        eval_sample(sR, la, w, imin[si], sc, np, ds, dn);
        nbuf0[s * HW + row + w] = dn;
    }

    grid.sync();

    // ---- round 1: vertical, nbuf0 -> sN (LDS only) ----
    #pragma unroll 1
    for (int si = 0; si < SG; ++si) {
        const int s = s0 + si;
        float np[3];
        #pragma unroll
        for (int c = 0; c < 3; ++c) {
            const int y = h + c - 1;
            np[c] = (y >= 0 && y < H) ? nbuf0[s * HW + y * W + w] : 0.0f;
        }
        float ds, dn;
        eval_sample(sR, la, w, imin[si], sc, np, ds, dn);
        sN[si * NPITCH + 1 + w] = dn;
    }

    __syncthreads();

    // ---- round 2: horizontal, sN -> nbuf1 ----
    #pragma unroll 1
    for (int si = 0; si < SG; ++si) {
        const int s = s0 + si;
        float np[3];
        #pragma unroll
        for (int c = 0; c < 3; ++c)
            np[c] = sN[si * NPITCH + w + c];   // pads give 0 at edges
        float ds, dn;
        eval_sample(sR, la, w, imin[si], sc, np, ds, dn);
        nbuf1[s * HW + row + w] = dn;
    }

    grid.sync();

    // ---- round 3: vertical, nbuf1 -> disp_out ----
    #pragma unroll 1
    for (int si = 0; si < SG; ++si) {
        const int s = s0 + si;
        float np[3];
        #pragma unroll
        for (int c = 0; c < 3; ++c) {
            const int y = h + c - 1;
            np[c] = (y >= 0 && y < H) ? nbuf1[s * HW + y * W + w] : 0.0f;
        }
        float ds, dn;
        eval_sample(sR, la, w, imin[si], sc, np, ds, dn);
        disp_out[s * HW + row + w] = ds;
    }
}

// ---------------- fallback: 3-kernel split (identical math) ----------------
// PHASE 0: round 0 (horizontal) noise_in -> nbuf0
// PHASE 1: round 1 (vertical, nbuf0) -> LDS -> round 2 (horizontal) -> nbuf1
// PHASE 2: round 3 (vertical, nbuf1) -> disp_out
template <int PHASE>
__global__ __launch_bounds__(256, 2) void pm_part(
    const float* __restrict__ left,
    const float* __restrict__ right,
    const float* __restrict__ min_disp,
    const float* __restrict__ max_disp,
    const float* __restrict__ nin,
    float* __restrict__ nout)
{
    __shared__ float sR[C * PITCH];
    __shared__ float sN[SG * NPITCH];

    const int w  = threadIdx.x;
    const int h  = blockIdx.x;
    const int s0 = SG * blockIdx.y;
    const int row = h * W;

    float la[C], sc, imin[SG];
    stage_block(left, right, min_disp, max_disp, sR, w, row, la, sc, imin, s0);
    if (PHASE == 1 && w < SG) {
        sN[w * NPITCH + 0]     = 0.0f;
        sN[w * NPITCH + W + 1] = 0.0f;
    }
    __syncthreads();

    #pragma unroll 1
    for (int si = 0; si < SG; ++si) {
        const int s = s0 + si;
        float np[3];
        #pragma unroll
        for (int c = 0; c < 3; ++c) {
            if (PHASE == 0) {
                const int x = w + c - 1;
                np[c] = (x >= 0 && x < W) ? nin[s * HW + row + x] : 0.0f;
            } else {
                const int y = h + c - 1;
                np[c] = (y >= 0 && y < H) ? nin[s * HW + y * W + w] : 0.0f;
            }
        }
        float ds, dn;
        eval_sample(sR, la, w, imin[si], sc, np, ds, dn);
        if (PHASE == 1) sN[si * NPITCH + 1 + w] = dn;
        else            nout[s * HW + row + w] = (PHASE == 2) ? ds : dn;
    }

    if (PHASE == 1) {
        __syncthreads();
        #pragma unroll 1
        for (int si = 0; si < SG; ++si) {
            const int s = s0 + si;
            float np[3];
            #pragma unroll
            for (int c = 0; c < 3; ++c)
                np[c] = sN[si * NPITCH + w + c];
            float ds, dn;
            eval_sample(sR, la, w, imin[si], sc, np, ds, dn);
            nout[s * HW + row + w] = dn;
        }
    }
}

extern "C" void kernel_launch(void* const* d_in, const int* in_sizes, int n_in,
                              void* d_out, int out_size, void* d_ws, size_t ws_size,
                              hipStream_t stream) {
    const float* left  = (const float*)d_in[0];
    const float* right = (const float*)d_in[1];
    const float* mind  = (const float*)d_in[2];
    const float* maxd  = (const float*)d_in[3];
    const float* noise = (const float*)d_in[4];
    float* out   = (float*)d_out;
    float* nbuf0 = (float*)d_ws;               // S*H*W floats = 1.5 MB
    float* nbuf1 = nbuf0 + S * HW;             // next 1.5 MB

    dim3 grid(H, GY);    // 128 x 4 = 512 blocks, 2 blocks/CU guaranteed
    dim3 block(256);

    void* args[] = {
        (void*)&left, (void*)&right, (void*)&mind, (void*)&maxd,
        (void*)&noise, (void*)&nbuf0, (void*)&nbuf1, (void*)&out
    };
    hipError_t err = hipLaunchCooperativeKernel(
        (const void*)pm_fused, grid, block, args, 0, stream);
    if (err != hipSuccess) {
        (void)hipGetLastError();   // clear error state, use split path
        pm_part<0><<<grid, block, 0, stream>>>(left, right, mind, maxd, noise, nbuf0);
        pm_part<1><<<grid, block, 0, stream>>>(left, right, mind, maxd, nbuf0, nbuf1);
        pm_part<2><<<grid, block, 0, stream>>>(left, right, mind, maxd, nbuf1, out);
    }
}